// Round 5
// baseline (310.719 us; speedup 1.0000x reference)
//
#include <hip/hip_runtime.h>
#include <hip/hip_bf16.h>
#include <cstdint>

// SelfSimilarity: out[b,i,j] = softmax_j( -T * max(||x_i - x_j||^2, 0) )
// bf16 MFMA via norm expansion; ||x||^2 computed from ROUNDED bf16 values so
// the diagonal logit is exactly 0 => max logit is 0 => no online max needed.
//
// V5: drop nontemporal stores. V4 counters (WRITE=343MB for 134MB out,
// FETCH=103MB, 2.4TB/s) showed NT's evict-ASAP flushes each 128B line
// half-dirty between the op0/op1 store pair -> RMW fetch + double write.
// Plain stores let the line become fully dirty in L2 (op0/op1 are
// back-to-back in the same wave) -> one full-line writeback, no fetch.
// L2 pollution is a non-issue: pinned B panel is 512KB/XCD, xbf fits L3.
// Keeps: swapped-operand MFMA (lane-local row, float4 epilogue), batch->XCD
// pinning (blk&7), two-sweep recompute (low VGPR, stores overlap compute).

using bf16x8 = __attribute__((ext_vector_type(8))) short;
using f32x4  = __attribute__((ext_vector_type(4))) float;

#define TEMP   (1.0f / 13.544f)
#define LOG2E  1.4426950408889634f

// ---------------------------------------------------------------------------
// prep: fp32 -> bf16 (RNE) in MFMA-staging layout + csq[row] = -T*log2e*||x_bf||^2
// ws bf16 layout: [b][group=row>>4][qblock=k>>3][r=row&15][8 elems]
//   -> uint4 index: (b*128+g)*256 + q*16 + r
// ---------------------------------------------------------------------------
__global__ __launch_bounds__(256) void prep_kernel(
    const float* __restrict__ x, uint4* __restrict__ xbf, float* __restrict__ csq)
{
    const int t   = threadIdx.x;
    const int lr  = t >> 4;            // local row 0..15
    const int q   = t & 15;            // k-block of 8
    const int row = blockIdx.x * 16 + lr;   // 0..16383

    const float* xp = x + (size_t)row * 128 + q * 8;
    float4 a0 = *(const float4*)(xp);
    float4 a1 = *(const float4*)(xp + 4);
    float v[8] = {a0.x, a0.y, a0.z, a0.w, a1.x, a1.y, a1.z, a1.w};

    unsigned u[8];
    float s = 0.f;
#pragma unroll
    for (int e = 0; e < 8; ++e) {
        unsigned ui = __float_as_uint(v[e]);
        unsigned r  = (ui + 0x7FFFu + ((ui >> 16) & 1u)) >> 16;   // RNE to bf16
        u[e] = r;
        float d = __uint_as_float(r << 16);                        // decoded value
        s += d * d;                                                // norm of ROUNDED vec
    }
    uint4 pack;
    pack.x = u[0] | (u[1] << 16);
    pack.y = u[2] | (u[3] << 16);
    pack.z = u[4] | (u[5] << 16);
    pack.w = u[6] | (u[7] << 16);

    const int b  = row >> 11;
    const int g  = (row >> 4) & 127;
    const int rr = row & 15;
    xbf[(b * 128 + g) * 256 + q * 16 + rr] = pack;

#pragma unroll
    for (int m = 1; m < 16; m <<= 1) s += __shfl_xor(s, m, 64);
    if (q == 0) csq[row] = s * (-TEMP * LOG2E);
}

// ---------------------------------------------------------------------------
// main: per workgroup, M=16 rows x all 2048 cols, two sweeps.
// 4 waves split each 128-col j-tile (wave w -> cols w*32..w*32+31).
// Swapped MFMA: acc[n][r] = out[i0 + l15][jt*128 + w*32 + n*16 + quad*4 + r]
// -> lane-local row, 4 consecutive cols per fragment -> float4 stores.
// logit2 = log2e*(-T*dist) = C2L*dot + csq_i + csq_j, clamped <= 0.
// ---------------------------------------------------------------------------
__global__ __launch_bounds__(256, 4) void sim_kernel(
    const uint4* __restrict__ xbf, const float* __restrict__ csq, float* __restrict__ out)
{
    const int blk  = blockIdx.x;
    const int b    = blk & 7;             // batch pinned to XCD (round-robin dispatch)
    const int i0   = (blk >> 3) * 16;     // 128 row-tiles per batch
    const int tid  = threadIdx.x;
    const int w    = tid >> 6;
    const int lane = tid & 63;
    const int quad = lane >> 4;
    const int l15  = lane & 15;

    __shared__ float lsSum[4][16];
    __shared__ __align__(16) float lsInv[16];

    const uint4* xbb  = xbf + (size_t)b * (128 * 256);
    const float* csqb = csq + b * 2048;

    // A fragments (i-rows): lane holds row i0+l15, k-chunk k4*4+quad.
    bf16x8 afrag[4];
#pragma unroll
    for (int k4 = 0; k4 < 4; ++k4) {
        uint4 vv = xbb[(i0 >> 4) * 256 + (k4 * 4 + quad) * 16 + l15];
        afrag[k4] = __builtin_bit_cast(bf16x8, vv);
    }

    const float csqi = csqb[i0 + l15];    // i is lane-local after the swap
    const float C2L  = 2.0f * TEMP * LOG2E;
    const int   c0   = w * 32;

    // ---- sweep 1: row sums only -------------------------------------------
    float sum_ = 0.f;
#pragma unroll
    for (int jt = 0; jt < 16; ++jt) {
        const int j0 = jt * 128;
        float4 cj0 = *(const float4*)(csqb + j0 + c0 + quad * 4);
        float4 cj1 = *(const float4*)(csqb + j0 + c0 + 16 + quad * 4);

        const uint4* b0p = xbb + (size_t)(jt * 8 + w * 2 + 0) * 256 + quad * 16 + l15;
        const uint4* b1p = b0p + 256;

        f32x4 acc[2] = {};
#pragma unroll
        for (int k4 = 0; k4 < 4; ++k4) {
            bf16x8 b0 = __builtin_bit_cast(bf16x8, b0p[k4 * 64]);
            bf16x8 b1 = __builtin_bit_cast(bf16x8, b1p[k4 * 64]);
            // swapped operands: D[j][i] -> lane = i, reg = j
            acc[0] = __builtin_amdgcn_mfma_f32_16x16x32_bf16(b0, afrag[k4], acc[0], 0, 0, 0);
            acc[1] = __builtin_amdgcn_mfma_f32_16x16x32_bf16(b1, afrag[k4], acc[1], 0, 0, 0);
        }

#pragma unroll
        for (int r = 0; r < 4; ++r) {
            float cj0r = (r == 0) ? cj0.x : (r == 1) ? cj0.y : (r == 2) ? cj0.z : cj0.w;
            float cj1r = (r == 0) ? cj1.x : (r == 1) ? cj1.y : (r == 2) ? cj1.z : cj1.w;
            sum_ += exp2f(fminf(fmaf(C2L, acc[0][r], csqi + cj0r), 0.f));
            sum_ += exp2f(fminf(fmaf(C2L, acc[1][r], csqi + cj1r), 0.f));
        }
    }

    // ---- reduce: across quads (lane bits 4,5), then across waves ----------
    sum_ += __shfl_xor(sum_, 16, 64);
    sum_ += __shfl_xor(sum_, 32, 64);
    if (quad == 0) lsSum[w][l15] = sum_;
    __syncthreads();
    if (tid < 16) {
        lsInv[tid] = 1.0f / (lsSum[0][tid] + lsSum[1][tid] + lsSum[2][tid] + lsSum[3][tid]);
    }
    __syncthreads();
    const float inv = lsInv[l15];

    // ---- sweep 2: recompute (B panel L2-hot), scale, float4 stores --------
    // per store: 64 lanes x 16B; rows l15 (16 rows), 64B contiguous per row;
    // the n=0/n=1 pair completes each 128B line while it is L2-resident.
    float* orow = out + ((size_t)b * 2048 + i0 + l15) * 2048;
#pragma unroll
    for (int jt = 0; jt < 16; ++jt) {
        const int j0 = jt * 128;
        float4 cj0 = *(const float4*)(csqb + j0 + c0 + quad * 4);
        float4 cj1 = *(const float4*)(csqb + j0 + c0 + 16 + quad * 4);

        const uint4* b0p = xbb + (size_t)(jt * 8 + w * 2 + 0) * 256 + quad * 16 + l15;
        const uint4* b1p = b0p + 256;

        f32x4 acc[2] = {};
#pragma unroll
        for (int k4 = 0; k4 < 4; ++k4) {
            bf16x8 b0 = __builtin_bit_cast(bf16x8, b0p[k4 * 64]);
            bf16x8 b1 = __builtin_bit_cast(bf16x8, b1p[k4 * 64]);
            acc[0] = __builtin_amdgcn_mfma_f32_16x16x32_bf16(b0, afrag[k4], acc[0], 0, 0, 0);
            acc[1] = __builtin_amdgcn_mfma_f32_16x16x32_bf16(b1, afrag[k4], acc[1], 0, 0, 0);
        }

        f32x4 p0, p1;
        p0[0] = exp2f(fminf(fmaf(C2L, acc[0][0], csqi + cj0.x), 0.f)) * inv;
        p0[1] = exp2f(fminf(fmaf(C2L, acc[0][1], csqi + cj0.y), 0.f)) * inv;
        p0[2] = exp2f(fminf(fmaf(C2L, acc[0][2], csqi + cj0.z), 0.f)) * inv;
        p0[3] = exp2f(fminf(fmaf(C2L, acc[0][3], csqi + cj0.w), 0.f)) * inv;
        p1[0] = exp2f(fminf(fmaf(C2L, acc[1][0], csqi + cj1.x), 0.f)) * inv;
        p1[1] = exp2f(fminf(fmaf(C2L, acc[1][1], csqi + cj1.y), 0.f)) * inv;
        p1[2] = exp2f(fminf(fmaf(C2L, acc[1][2], csqi + cj1.z), 0.f)) * inv;
        p1[3] = exp2f(fminf(fmaf(C2L, acc[1][3], csqi + cj1.w), 0.f)) * inv;

        *(f32x4*)(orow + j0 + c0 + quad * 4)      = p0;
        *(f32x4*)(orow + j0 + c0 + 16 + quad * 4) = p1;
    }
}

extern "C" void kernel_launch(void* const* d_in, const int* in_sizes, int n_in,
                              void* d_out, int out_size, void* d_ws, size_t ws_size,
                              hipStream_t stream) {
    const float* x   = (const float*)d_in[0];
    float*       out = (float*)d_out;
    // ws: [0, 4MB) packed bf16 x; [4MB, 4MB+64KB) csq. Needs ~4.26 MB of ws.
    uint4* xbf = (uint4*)d_ws;
    float* csq = (float*)((char*)d_ws + (size_t)4 * 1024 * 1024);

    prep_kernel<<<1024, 256, 0, stream>>>(x, xbf, csq);     // 16384 rows
    sim_kernel<<<1024, 256, 0, stream>>>(xbf, csq, out);    // 8 batches x 128 row-tiles
}

// Round 7
// 304.356 us; speedup vs baseline: 1.0209x; 1.0209x over previous
//
#include <hip/hip_runtime.h>
#include <hip/hip_bf16.h>
#include <cstdint>

// SelfSimilarity: out[b,i,j] = softmax_j( -T * max(||x_i - x_j||^2, 0) )
// bf16 MFMA via norm expansion; ||x||^2 computed from ROUNDED bf16 values so
// the diagonal logit is exactly 0 => max logit is 0 => no online max needed.
//
// V6: full-line stores via LDS-transposed epilogue. V3/V4/V5 counters all
// showed WRITE ~2.5x output + FETCH ~0.8x output independent of NT and of
// fragment size: no store instruction covered a full 128B line, and the
// compiler's unroll scheduling separated a line's two half-writes far
// enough that L2 evicted lines half-dirty (partial writeback + allocate
// fetch + second writeback). Geometric fix: stage each 16x128 P-tile in
// LDS (XOR-swizzled, double-buffered, 1 barrier/tile), then store flat:
// each global dwordx4 wave-op writes 2x512B contiguous row segments, so
// every 128B line is fully written by ONE instruction. Keeps: swapped
// MFMA, batch->XCD pinning, two-sweep recompute, direct-from-L2 B loads.
// (resubmit: round-6 bench was an infra failure, kernel unchanged)

using bf16x8 = __attribute__((ext_vector_type(8))) short;
using f32x4  = __attribute__((ext_vector_type(4))) float;

#define TEMP   (1.0f / 13.544f)
#define LOG2E  1.4426950408889634f

// ---------------------------------------------------------------------------
// prep: fp32 -> bf16 (RNE) in MFMA-staging layout + csq[row] = -T*log2e*||x_bf||^2
// ws bf16 layout: [b][group=row>>4][qblock=k>>3][r=row&15][8 elems]
//   -> uint4 index: (b*128+g)*256 + q*16 + r
// ---------------------------------------------------------------------------
__global__ __launch_bounds__(256) void prep_kernel(
    const float* __restrict__ x, uint4* __restrict__ xbf, float* __restrict__ csq)
{
    const int t   = threadIdx.x;
    const int lr  = t >> 4;            // local row 0..15
    const int q   = t & 15;            // k-block of 8
    const int row = blockIdx.x * 16 + lr;   // 0..16383

    const float* xp = x + (size_t)row * 128 + q * 8;
    float4 a0 = *(const float4*)(xp);
    float4 a1 = *(const float4*)(xp + 4);
    float v[8] = {a0.x, a0.y, a0.z, a0.w, a1.x, a1.y, a1.z, a1.w};

    unsigned u[8];
    float s = 0.f;
#pragma unroll
    for (int e = 0; e < 8; ++e) {
        unsigned ui = __float_as_uint(v[e]);
        unsigned r  = (ui + 0x7FFFu + ((ui >> 16) & 1u)) >> 16;   // RNE to bf16
        u[e] = r;
        float d = __uint_as_float(r << 16);                        // decoded value
        s += d * d;                                                // norm of ROUNDED vec
    }
    uint4 pack;
    pack.x = u[0] | (u[1] << 16);
    pack.y = u[2] | (u[3] << 16);
    pack.z = u[4] | (u[5] << 16);
    pack.w = u[6] | (u[7] << 16);

    const int b  = row >> 11;
    const int g  = (row >> 4) & 127;
    const int rr = row & 15;
    xbf[(b * 128 + g) * 256 + q * 16 + rr] = pack;

#pragma unroll
    for (int m = 1; m < 16; m <<= 1) s += __shfl_xor(s, m, 64);
    if (q == 0) csq[row] = s * (-TEMP * LOG2E);
}

// ---------------------------------------------------------------------------
// main: per workgroup, M=16 rows x all 2048 cols, two sweeps.
// 4 waves split each 128-col j-tile (wave w -> cols w*32..w*32+31).
// Swapped MFMA: acc[n][r] = out[i0 + l15][jt*128 + w*32 + n*16 + quad*4 + r]
// -> lane-local row. Sweep 2 stages each scaled 16x128 tile in LDS and
// stores it flat-contiguous (full 128B lines per instruction).
// logit2 = log2e*(-T*dist) = C2L*dot + csq_i + csq_j, clamped <= 0.
// ---------------------------------------------------------------------------
__global__ __launch_bounds__(256, 4) void sim_kernel(
    const uint4* __restrict__ xbf, const float* __restrict__ csq, float* __restrict__ out)
{
    const int blk  = blockIdx.x;
    const int b    = blk & 7;             // batch pinned to XCD (round-robin dispatch)
    const int i0   = (blk >> 3) * 16;     // 128 row-tiles per batch
    const int tid  = threadIdx.x;
    const int w    = tid >> 6;
    const int lane = tid & 63;
    const int quad = lane >> 4;
    const int l15  = lane & 15;

    __shared__ __align__(16) char lsP[2][8192];   // double-buffered 16x128 f32 tile
    __shared__ float lsSum[4][16];
    __shared__ __align__(16) float lsInv[16];

    const uint4* xbb  = xbf + (size_t)b * (128 * 256);
    const float* csqb = csq + b * 2048;

    // A fragments (i-rows): lane holds row i0+l15, k-chunk k4*4+quad.
    bf16x8 afrag[4];
#pragma unroll
    for (int k4 = 0; k4 < 4; ++k4) {
        uint4 vv = xbb[(i0 >> 4) * 256 + (k4 * 4 + quad) * 16 + l15];
        afrag[k4] = __builtin_bit_cast(bf16x8, vv);
    }

    const float csqi = csqb[i0 + l15];    // i is lane-local after the swap
    const float C2L  = 2.0f * TEMP * LOG2E;
    const int   c0   = w * 32;

    // ---- sweep 1: row sums only -------------------------------------------
    float sum_ = 0.f;
#pragma unroll
    for (int jt = 0; jt < 16; ++jt) {
        const int j0 = jt * 128;
        float4 cj0 = *(const float4*)(csqb + j0 + c0 + quad * 4);
        float4 cj1 = *(const float4*)(csqb + j0 + c0 + 16 + quad * 4);

        const uint4* b0p = xbb + (size_t)(jt * 8 + w * 2 + 0) * 256 + quad * 16 + l15;
        const uint4* b1p = b0p + 256;

        f32x4 acc[2] = {};
#pragma unroll
        for (int k4 = 0; k4 < 4; ++k4) {
            bf16x8 b0 = __builtin_bit_cast(bf16x8, b0p[k4 * 64]);
            bf16x8 b1 = __builtin_bit_cast(bf16x8, b1p[k4 * 64]);
            // swapped operands: D[j][i] -> lane = i, reg = j
            acc[0] = __builtin_amdgcn_mfma_f32_16x16x32_bf16(b0, afrag[k4], acc[0], 0, 0, 0);
            acc[1] = __builtin_amdgcn_mfma_f32_16x16x32_bf16(b1, afrag[k4], acc[1], 0, 0, 0);
        }

#pragma unroll
        for (int r = 0; r < 4; ++r) {
            float cj0r = (r == 0) ? cj0.x : (r == 1) ? cj0.y : (r == 2) ? cj0.z : cj0.w;
            float cj1r = (r == 0) ? cj1.x : (r == 1) ? cj1.y : (r == 2) ? cj1.z : cj1.w;
            sum_ += exp2f(fminf(fmaf(C2L, acc[0][r], csqi + cj0r), 0.f));
            sum_ += exp2f(fminf(fmaf(C2L, acc[1][r], csqi + cj1r), 0.f));
        }
    }

    // ---- reduce: across quads (lane bits 4,5), then across waves ----------
    sum_ += __shfl_xor(sum_, 16, 64);
    sum_ += __shfl_xor(sum_, 32, 64);
    if (quad == 0) lsSum[w][l15] = sum_;
    __syncthreads();
    if (tid < 16) {
        lsInv[tid] = 1.0f / (lsSum[0][tid] + lsSum[1][tid] + lsSum[2][tid] + lsSum[3][tid]);
    }
    __syncthreads();
    const float inv = lsInv[l15];

    // ---- sweep 2: recompute, scale, LDS-transpose, full-line store --------
    // Epilogue indexing: flat float idx tid*4 in the 16x128 tile (+1024 for
    // the second half): rows tid>>5 and 8+(tid>>5), col (tid&31)*4.
    const int rowA = tid >> 5;                // 0..7
    const int rowB = rowA + 8;
    const int cb   = (tid & 31) << 4;         // byte offset within 512B row
    const int rswz = (rowA & 7) << 4;         // rowB&7 == rowA&7 -> same swizzle
    float* obase = out + ((size_t)b * 2048 + i0) * 2048;

#pragma unroll
    for (int jt = 0; jt < 16; ++jt) {
        const int j0 = jt * 128;
        float4 cj0 = *(const float4*)(csqb + j0 + c0 + quad * 4);
        float4 cj1 = *(const float4*)(csqb + j0 + c0 + 16 + quad * 4);

        const uint4* b0p = xbb + (size_t)(jt * 8 + w * 2 + 0) * 256 + quad * 16 + l15;
        const uint4* b1p = b0p + 256;

        f32x4 acc[2] = {};
#pragma unroll
        for (int k4 = 0; k4 < 4; ++k4) {
            bf16x8 b0 = __builtin_bit_cast(bf16x8, b0p[k4 * 64]);
            bf16x8 b1 = __builtin_bit_cast(bf16x8, b1p[k4 * 64]);
            acc[0] = __builtin_amdgcn_mfma_f32_16x16x32_bf16(b0, afrag[k4], acc[0], 0, 0, 0);
            acc[1] = __builtin_amdgcn_mfma_f32_16x16x32_bf16(b1, afrag[k4], acc[1], 0, 0, 0);
        }

        f32x4 p0, p1;
        p0[0] = exp2f(fminf(fmaf(C2L, acc[0][0], csqi + cj0.x), 0.f)) * inv;
        p0[1] = exp2f(fminf(fmaf(C2L, acc[0][1], csqi + cj0.y), 0.f)) * inv;
        p0[2] = exp2f(fminf(fmaf(C2L, acc[0][2], csqi + cj0.z), 0.f)) * inv;
        p0[3] = exp2f(fminf(fmaf(C2L, acc[0][3], csqi + cj0.w), 0.f)) * inv;
        p1[0] = exp2f(fminf(fmaf(C2L, acc[1][0], csqi + cj1.x), 0.f)) * inv;
        p1[1] = exp2f(fminf(fmaf(C2L, acc[1][1], csqi + cj1.y), 0.f)) * inv;
        p1[2] = exp2f(fminf(fmaf(C2L, acc[1][2], csqi + cj1.z), 0.f)) * inv;
        p1[3] = exp2f(fminf(fmaf(C2L, acc[1][3], csqi + cj1.w), 0.f)) * inv;

        // LDS write: row l15 (512B stride), cols c0+quad*4 (+16). XOR-swizzle
        // 16B slots by row&7 so the 16 same-column rows spread across banks.
        char* buf = lsP[jt & 1];
        {
            const int wr  = l15 << 9;                  // l15 * 512
            const int ws  = (l15 & 7) << 4;
            const int wc0 = (c0 << 2) + (quad << 4);   // byte col of p0
            *(f32x4*)(buf + wr + ((wc0)      ^ ws)) = p0;
            *(f32x4*)(buf + wr + ((wc0 + 64) ^ ws)) = p1;
        }
        __syncthreads();

        // flat contiguous read-back + store: per wave-op, 2 rows x 512B
        // contiguous segments -> every 128B line written by one instruction.
        f32x4 vA = *(const f32x4*)(buf + (rowA << 9) + (cb ^ rswz));
        f32x4 vB = *(const f32x4*)(buf + (rowB << 9) + (cb ^ rswz));
        *(f32x4*)(obase + (size_t)rowA * 2048 + j0 + (tid & 31) * 4) = vA;
        *(f32x4*)(obase + (size_t)rowB * 2048 + j0 + (tid & 31) * 4) = vB;
        // no second barrier: next jt writes the other buffer; reads of this
        // buffer are lgkmcnt-complete before the stores (and thus before the
        // next iteration's barrier).
    }
}

extern "C" void kernel_launch(void* const* d_in, const int* in_sizes, int n_in,
                              void* d_out, int out_size, void* d_ws, size_t ws_size,
                              hipStream_t stream) {
    const float* x   = (const float*)d_in[0];
    float*       out = (float*)d_out;
    // ws: [0, 4MB) packed bf16 x; [4MB, 4MB+64KB) csq. Needs ~4.26 MB of ws.
    uint4* xbf = (uint4*)d_ws;
    float* csq = (float*)((char*)d_ws + (size_t)4 * 1024 * 1024);

    prep_kernel<<<1024, 256, 0, stream>>>(x, xbf, csq);     // 16384 rows
    sim_kernel<<<1024, 256, 0, stream>>>(xbf, csq, out);    // 8 batches x 128 row-tiles
}

// Round 8
// 155.917 us; speedup vs baseline: 1.9928x; 1.9520x over previous
//
#include <hip/hip_runtime.h>
#include <hip/hip_bf16.h>
#include <cstdint>

// SelfSimilarity: out[b,i,j] = softmax_j( -T * max(||x_i - x_j||^2, 0) )
// bf16 MFMA via norm expansion; ||x||^2 from ROUNDED bf16 values so the
// diagonal logit is exactly 0 => max logit 0 => no online max needed.
//
// V7: recombination of proven-fast pieces. Timing ledger V0..V6 showed:
// each full sweep (B-loads+MFMA+exp2) costs ~85-100us; store mechanics are
// a small additive term (V3 218 -> V6 189 across radical store changes;
// WRITE stayed ~2.5x output even with guaranteed full-line stores -> L2
// policy artifact, not controllable). So: SINGLE sweep (V0's structure,
// P in regs, launch_bounds(256,2)) + swapped-operand MFMA (V4, verified:
// lane-local output row) + LDS full-line epilogue (V6, verified swizzle,
// 0 bank conflicts) replacing V0's scalar store burst. Direct-L2 B loads
// (V2 ~= V0), no barriers in the sweep.

using bf16x8 = __attribute__((ext_vector_type(8))) short;
using f32x4  = __attribute__((ext_vector_type(4))) float;

#define TEMP   (1.0f / 13.544f)
#define LOG2E  1.4426950408889634f

// ---------------------------------------------------------------------------
// prep: fp32 -> bf16 (RNE) in MFMA-staging layout + csq[row] = -T*log2e*||x_bf||^2
// ws bf16 layout: [b][group=row>>4][qblock=k>>3][r=row&15][8 elems]
//   -> uint4 index: (b*128+g)*256 + q*16 + r
// ---------------------------------------------------------------------------
__global__ __launch_bounds__(256) void prep_kernel(
    const float* __restrict__ x, uint4* __restrict__ xbf, float* __restrict__ csq)
{
    const int t   = threadIdx.x;
    const int lr  = t >> 4;            // local row 0..15
    const int q   = t & 15;            // k-block of 8
    const int row = blockIdx.x * 16 + lr;   // 0..16383

    const float* xp = x + (size_t)row * 128 + q * 8;
    float4 a0 = *(const float4*)(xp);
    float4 a1 = *(const float4*)(xp + 4);
    float v[8] = {a0.x, a0.y, a0.z, a0.w, a1.x, a1.y, a1.z, a1.w};

    unsigned u[8];
    float s = 0.f;
#pragma unroll
    for (int e = 0; e < 8; ++e) {
        unsigned ui = __float_as_uint(v[e]);
        unsigned r  = (ui + 0x7FFFu + ((ui >> 16) & 1u)) >> 16;   // RNE to bf16
        u[e] = r;
        float d = __uint_as_float(r << 16);                        // decoded value
        s += d * d;                                                // norm of ROUNDED vec
    }
    uint4 pack;
    pack.x = u[0] | (u[1] << 16);
    pack.y = u[2] | (u[3] << 16);
    pack.z = u[4] | (u[5] << 16);
    pack.w = u[6] | (u[7] << 16);

    const int b  = row >> 11;
    const int g  = (row >> 4) & 127;
    const int rr = row & 15;
    xbf[(b * 128 + g) * 256 + q * 16 + rr] = pack;

#pragma unroll
    for (int m = 1; m < 16; m <<= 1) s += __shfl_xor(s, m, 64);
    if (q == 0) csq[row] = s * (-TEMP * LOG2E);
}

// ---------------------------------------------------------------------------
// main: per workgroup, M=16 rows x all 2048 cols, ONE sweep.
// 4 waves split each 128-col j-tile (wave w -> cols w*32..w*32+31).
// Swapped MFMA: acc[n][r] = out[i0 + l15][jt*128 + w*32 + n*16 + quad*4 + r]
// -> lane-local row, 4 consecutive cols per fragment. P kept in registers
// (16 tiles x 2 x f32x4 = 128 fp32/lane), sums inline; after the inv
// reduction, a 4-round LDS-transposed epilogue emits full-128B-line stores.
// logit2 = log2e*(-T*dist) = C2L*dot + csq_i + csq_j, clamped <= 0.
// ---------------------------------------------------------------------------
__global__ __launch_bounds__(256, 2) void sim_kernel(
    const uint4* __restrict__ xbf, const float* __restrict__ csq, float* __restrict__ out)
{
    const int blk  = blockIdx.x;
    const int b    = blk & 7;             // batch pinned to XCD (round-robin dispatch)
    const int i0   = (blk >> 3) * 16;     // 128 row-tiles per batch
    const int tid  = threadIdx.x;
    const int w    = tid >> 6;
    const int lane = tid & 63;
    const int quad = lane >> 4;
    const int l15  = lane & 15;

    __shared__ __align__(16) char lsP[4][8192];   // epilogue: 4 x (16x128 f32 tile)
    __shared__ float lsSum[4][16];
    __shared__ __align__(16) float lsInv[16];

    const uint4* xbb  = xbf + (size_t)b * (128 * 256);
    const float* csqb = csq + b * 2048;

    // A fragments (i-rows): lane holds row i0+l15, k-chunk k4*4+quad.
    bf16x8 afrag[4];
#pragma unroll
    for (int k4 = 0; k4 < 4; ++k4) {
        uint4 vv = xbb[(i0 >> 4) * 256 + (k4 * 4 + quad) * 16 + l15];
        afrag[k4] = __builtin_bit_cast(bf16x8, vv);
    }

    const float csqi = csqb[i0 + l15];    // i is lane-local after the swap
    const float C2L  = 2.0f * TEMP * LOG2E;
    const int   c0   = w * 32;

    // ---- single sweep: P into registers, row sums inline ------------------
    f32x4 P0[16], P1[16];
    float sum_ = 0.f;
#pragma unroll
    for (int jt = 0; jt < 16; ++jt) {
        const int j0 = jt * 128;
        float4 cj0 = *(const float4*)(csqb + j0 + c0 + quad * 4);
        float4 cj1 = *(const float4*)(csqb + j0 + c0 + 16 + quad * 4);

        // B fragments direct from L2: 64 lanes x 16B contiguous per wave-op.
        const uint4* b0p = xbb + (size_t)(jt * 8 + w * 2 + 0) * 256 + quad * 16 + l15;
        const uint4* b1p = b0p + 256;

        f32x4 acc[2] = {};
#pragma unroll
        for (int k4 = 0; k4 < 4; ++k4) {
            bf16x8 b0 = __builtin_bit_cast(bf16x8, b0p[k4 * 64]);
            bf16x8 b1 = __builtin_bit_cast(bf16x8, b1p[k4 * 64]);
            // swapped operands: lane = i-row, regs = 4 consecutive j
            acc[0] = __builtin_amdgcn_mfma_f32_16x16x32_bf16(b0, afrag[k4], acc[0], 0, 0, 0);
            acc[1] = __builtin_amdgcn_mfma_f32_16x16x32_bf16(b1, afrag[k4], acc[1], 0, 0, 0);
        }

        f32x4 p0, p1;
        p0[0] = exp2f(fminf(fmaf(C2L, acc[0][0], csqi + cj0.x), 0.f));
        p0[1] = exp2f(fminf(fmaf(C2L, acc[0][1], csqi + cj0.y), 0.f));
        p0[2] = exp2f(fminf(fmaf(C2L, acc[0][2], csqi + cj0.z), 0.f));
        p0[3] = exp2f(fminf(fmaf(C2L, acc[0][3], csqi + cj0.w), 0.f));
        p1[0] = exp2f(fminf(fmaf(C2L, acc[1][0], csqi + cj1.x), 0.f));
        p1[1] = exp2f(fminf(fmaf(C2L, acc[1][1], csqi + cj1.y), 0.f));
        p1[2] = exp2f(fminf(fmaf(C2L, acc[1][2], csqi + cj1.z), 0.f));
        p1[3] = exp2f(fminf(fmaf(C2L, acc[1][3], csqi + cj1.w), 0.f));
        P0[jt] = p0;
        P1[jt] = p1;
        sum_ += p0[0] + p0[1] + p0[2] + p0[3] + p1[0] + p1[1] + p1[2] + p1[3];
    }

    // ---- reduce: across quads (lane bits 4,5), then across waves ----------
    sum_ += __shfl_xor(sum_, 16, 64);
    sum_ += __shfl_xor(sum_, 32, 64);
    if (quad == 0) lsSum[w][l15] = sum_;
    __syncthreads();
    if (tid < 16) {
        lsInv[tid] = 1.0f / (lsSum[0][tid] + lsSum[1][tid] + lsSum[2][tid] + lsSum[3][tid]);
    }
    __syncthreads();
    const float inv = lsInv[l15];

    // ---- epilogue: 4 rounds x (LDS-transpose 4 tiles, full-line store) ----
    // LDS write: row l15 (512B stride), 16B slots XOR-swizzled by row&7
    // (verified in V6: correct + 0 bank conflicts). Read-back flat: per
    // wave-op 2 rows x 512B contiguous -> every 128B line written by ONE
    // global instruction.
    const int rowA = tid >> 5;                // 0..7
    const int rowB = rowA + 8;
    const int cb   = (tid & 31) << 4;         // byte offset within 512B row
    const int rswz = (rowA & 7) << 4;         // rowB&7 == rowA&7 -> same swizzle
    const int wr   = l15 << 9;                // l15 * 512
    const int ws   = (l15 & 7) << 4;
    const int wc0  = (c0 << 2) + (quad << 4); // byte col of p0
    float* obase = out + ((size_t)b * 2048 + i0) * 2048;

#pragma unroll
    for (int rd = 0; rd < 4; ++rd) {
#pragma unroll
        for (int t4 = 0; t4 < 4; ++t4) {
            const int jt = rd * 4 + t4;
            char* buf = lsP[t4];
            f32x4 s0 = P0[jt] * inv;
            f32x4 s1 = P1[jt] * inv;
            *(f32x4*)(buf + wr + ((wc0)      ^ ws)) = s0;
            *(f32x4*)(buf + wr + ((wc0 + 64) ^ ws)) = s1;
        }
        __syncthreads();
#pragma unroll
        for (int t4 = 0; t4 < 4; ++t4) {
            const int jt = rd * 4 + t4;
            const int j0 = jt * 128;
            char* buf = lsP[t4];
            f32x4 vA = *(const f32x4*)(buf + (rowA << 9) + (cb ^ rswz));
            f32x4 vB = *(const f32x4*)(buf + (rowB << 9) + (cb ^ rswz));
            *(f32x4*)(obase + (size_t)rowA * 2048 + j0 + (tid & 31) * 4) = vA;
            *(f32x4*)(obase + (size_t)rowB * 2048 + j0 + (tid & 31) * 4) = vB;
        }
        __syncthreads();   // before next round overwrites lsP
    }
}

extern "C" void kernel_launch(void* const* d_in, const int* in_sizes, int n_in,
                              void* d_out, int out_size, void* d_ws, size_t ws_size,
                              hipStream_t stream) {
    const float* x   = (const float*)d_in[0];
    float*       out = (float*)d_out;
    // ws: [0, 4MB) packed bf16 x; [4MB, 4MB+64KB) csq. Needs ~4.26 MB of ws.
    uint4* xbf = (uint4*)d_ws;
    float* csq = (float*)((char*)d_ws + (size_t)4 * 1024 * 1024);

    prep_kernel<<<1024, 256, 0, stream>>>(x, xbf, csq);     // 16384 rows
    sim_kernel<<<1024, 256, 0, stream>>>(xbf, csq, out);    // 8 batches x 128 row-tiles
}